// Round 2
// baseline (1278.486 us; speedup 1.0000x reference)
//
#include <hip/hip_runtime.h>
#include <hip/hip_bf16.h>
#include <math.h>

// MultiLayerGRUParallel: B=32, S=4096, H=128, OUT=128, L=3
// Fused pipeline: convw2 -> prep0t -> scan2 -> KB(l0->l1) -> scan2 -> KB(l1->l2)
//                 -> scan2 -> scan3v2 -> outmm -> outred
#define B_   32
#define S_   4096
#define H_   128
#define OUT_ 128
#define P_   (B_*S_)       // 131072 positions
#define NC_  64            // time chunks per chain
#define CH_  (S_/NC_)      // 64 steps per chunk
#define NKS_ 512           // split-K workgroups for final matmul
#define KTOT_ (H_*S_)      // 524288
#define NEGINF_ (-__builtin_inff())

typedef __bf16 bf16x8 __attribute__((ext_vector_type(8)));
typedef float  f32x4  __attribute__((ext_vector_type(4)));
typedef unsigned short ushort8_t __attribute__((ext_vector_type(8)));

__device__ __forceinline__ float sp_(float x) {           // softplus, stable
  return fmaxf(x, 0.f) + log1pf(__expf(-fabsf(x)));
}
__device__ __forceinline__ float logg_(float x) {          // _log_g
  return (x >= 0.f) ? __logf(x + 0.5f) : -sp_(-x);
}
__device__ __forceinline__ float lae_(float a, float b) {  // logaddexp
  float m = fmaxf(a, b);
  float d = fminf(a, b) - m;           // lae(-inf, x) = x; never both -inf here
  return m + log1pf(__expf(d));
}
__device__ __forceinline__ unsigned short f2bf_(float f) { // fp32->bf16 RNE
  unsigned int u = __float_as_uint(f);
  u += 0x7fffu + ((u >> 16) & 1u);
  return (unsigned short)(u >> 16);
}
__device__ __forceinline__ float wscan_(float v) {         // wave64 inclusive +scan
  int lane = threadIdx.x & 63;
  #pragma unroll
  for (int d = 1; d < 64; d <<= 1) {
    float t = __shfl_up(v, (unsigned)d, 64);
    if (lane >= d) v += t;
  }
  return v;
}

// ---------------- weight convert: [Wz;Wh] -> bf16 256x128 for layers 1,2 ----
__global__ __launch_bounds__(256) void convw2_kernel(
    const float* __restrict__ Wz1, const float* __restrict__ Wh1,
    const float* __restrict__ Wz2, const float* __restrict__ Wh2,
    unsigned short* __restrict__ Wc1, unsigned short* __restrict__ Wc2)
{
  int idx = blockIdx.x * 256 + threadIdx.x;  // < 32768
  Wc1[idx] = f2bf_(idx < 16384 ? Wz1[idx] : Wh1[idx - 16384]);
  Wc2[idx] = f2bf_(idx < 16384 ? Wz2[idx] : Wh2[idx - 16384]);
}

// ---------------- layer 0 prep + chunk totals ----------------
// block = one chunk (b,c); 128 thr = 2 waves; wave handles one position/iter.
__global__ __launch_bounds__(128) void prep0t_kernel(
    const float* __restrict__ x,
    const float* __restrict__ Wz, const float* __restrict__ bz,
    const float* __restrict__ Wh, const float* __restrict__ bh,
    float* __restrict__ u, float* __restrict__ A, float* __restrict__ tot)
{
  __shared__ float tl[128];
  int lane = threadIdx.x & 63, wid = threadIdx.x >> 6;
  float wz0 = Wz[lane], wz1 = Wz[lane + 64];
  float bz0 = bz[lane], bz1 = bz[lane + 64];
  float wh0 = Wh[lane], wh1 = Wh[lane + 64];
  float bh0 = bh[lane], bh1 = bh[lane + 64];
  int blk = blockIdx.x;                       // b*NC + c
  size_t base = (size_t)blk * (CH_ * H_);
  int pos0 = blk * CH_;
  float t0 = NEGINF_, t1 = NEGINF_;
  for (int j = 0; j < 32; ++j) {
    int i = j * 2 + wid;
    float xv = x[pos0 + i];
    float k0 = fmaf(xv, wz0, bz0), k1 = fmaf(xv, wz1, bz1);
    float g0 = fmaf(xv, wh0, bh0), g1 = fmaf(xv, wh1, bh1);
    float lc0 = -sp_(k0), lc1 = -sp_(k1);
    float lv0 = k0 + lc0 + logg_(g0);   // -sp(-k) == k - sp(k)
    float lv1 = k1 + lc1 + logg_(g1);
    float s0 = wscan_(lc0);
    float c0 = __shfl(s0, 63, 64);
    float s1 = wscan_(lc1) + c0;
    float u0 = lv0 - s0, u1 = lv1 - s1;
    size_t o = base + (size_t)i * H_;
    u[o + lane]      = u0;  u[o + 64 + lane] = u1;
    A[o + lane]      = s0;  A[o + 64 + lane] = s1;
    t0 = lae_(t0, u0); t1 = lae_(t1, u1);
  }
  if (wid == 0) { tl[lane] = t0; tl[64 + lane] = t1; }
  __syncthreads();
  if (wid == 1) {
    tot[(size_t)blk * H_ + lane]      = lae_(tl[lane], t0);
    tot[(size_t)blk * H_ + 64 + lane] = lae_(tl[64 + lane], t1);
  }
}

// ---------------- inter-chunk carry (tiny) ----------------
__global__ __launch_bounds__(128) void scan2_kernel(
    const float* __restrict__ tot, float* __restrict__ carry)
{
  int b = blockIdx.x, ch = threadIdx.x;
  float r = -0.6931471805599453f;  // log(0.5): the t=0 init value
  for (int c = 0; c < NC_; ++c) {
    size_t idx = (size_t)(b * NC_ + c) * H_ + ch;
    carry[idx] = r;
    r = lae_(r, tot[idx]);
  }
}

// ---------------- fused: scan3(layer l) + matmul xW(l+1) + epilogue + tot ----
// block = one chunk; 128 thr = 2 waves. h stays in LDS (bf16). u/A in-place.
__global__ __launch_bounds__(128) void kb_kernel(
    const float* __restrict__ carry,          // layer l carries
    const unsigned short* __restrict__ Wc,    // layer l+1 [256][128] bf16
    const float* __restrict__ bz, const float* __restrict__ bh,
    float* __restrict__ u, float* __restrict__ A,  // in: layer l, out: layer l+1
    float* __restrict__ tot)                  // out: layer l+1 chunk totals
{
  __shared__ unsigned short hT[64][128];  // 16 KB, h of layer l (bf16)
  __shared__ float kg[16][260];           // one 16-row m-tile of [k|g]
  __shared__ float tl[128];
  int tid = threadIdx.x;
  int lane = tid & 63, w = tid >> 6;
  int l15 = lane & 15, quad = lane >> 4;
  int blk = blockIdx.x;
  size_t base = (size_t)blk * (CH_ * H_);

  // ---- phase 1: time-scan of layer l, h -> LDS ----
  {
    int ch = tid;
    float r = carry[(size_t)blk * H_ + ch];
    const float* up = u + base + ch;
    const float* Ap = A + base + ch;
    for (int i0 = 0; i0 < CH_; i0 += 16) {
      float uv[16], av[16];
      #pragma unroll
      for (int i = 0; i < 16; ++i) { uv[i] = up[(i0 + i) * H_]; av[i] = Ap[(i0 + i) * H_]; }
      #pragma unroll
      for (int i = 0; i < 16; ++i) {
        r = lae_(r, uv[i]);
        float e = __expf(av[i] + r);
        float hv = 1.f / (1.f + __expf(-e));   // sigmoid(exp(log_h))
        hT[i0 + i][ch] = f2bf_(hv);
      }
    }
  }
  __syncthreads();

  float bz0v = bz[lane], bz1v = bz[lane + 64];
  float bh0v = bh[lane], bh1v = bh[lane + 64];
  float t0 = NEGINF_, t1 = NEGINF_;

  // ---- phase 2/3 per 16-row m-tile: MFMA then epilogue ----
  for (int t = 0; t < 4; ++t) {
    f32x4 z = {0.f, 0.f, 0.f, 0.f};
    f32x4 acc[8] = {z, z, z, z, z, z, z, z};
    #pragma unroll
    for (int kk = 0; kk < 4; ++kk) {
      bf16x8 a = *reinterpret_cast<const bf16x8*>(&hT[t * 16 + l15][kk * 32 + quad * 8]);
      #pragma unroll
      for (int nt = 0; nt < 8; ++nt) {
        int n = w * 128 + nt * 16 + l15;   // output col in [k|g] 256
        bf16x8 bf = *reinterpret_cast<const bf16x8*>(Wc + n * 128 + kk * 32 + quad * 8);
        acc[nt] = __builtin_amdgcn_mfma_f32_16x16x32_bf16(a, bf, acc[nt], 0, 0, 0);
      }
    }
    __syncthreads();  // previous epilogue done reading kg
    #pragma unroll
    for (int nt = 0; nt < 8; ++nt) {
      int col = w * 128 + nt * 16 + l15;
      #pragma unroll
      for (int r2 = 0; r2 < 4; ++r2)
        kg[quad * 4 + r2][col] = acc[nt][r2];   // D: row=quad*4+r2, col=l15
    }
    __syncthreads();
    #pragma unroll
    for (int i = 0; i < 8; ++i) {
      int row = w + i * 2;            // wave-interleaved rows of the m-tile
      int sIdx = t * 16 + row;
      float k0 = kg[row][lane]        + bz0v;
      float k1 = kg[row][64 + lane]   + bz1v;
      float g0 = kg[row][128 + lane]  + bh0v;
      float g1 = kg[row][192 + lane]  + bh1v;
      float lc0 = -sp_(k0), lc1 = -sp_(k1);
      float lv0 = k0 + lc0 + logg_(g0);
      float lv1 = k1 + lc1 + logg_(g1);
      float s0 = wscan_(lc0);
      float c0 = __shfl(s0, 63, 64);
      float s1 = wscan_(lc1) + c0;
      float u0 = lv0 - s0, u1 = lv1 - s1;
      size_t o = base + (size_t)sIdx * H_;
      u[o + lane]      = u0;  u[o + 64 + lane] = u1;
      A[o + lane]      = s0;  A[o + 64 + lane] = s1;
      t0 = lae_(t0, u0); t1 = lae_(t1, u1);
    }
  }

  // ---- combine chunk totals across the 2 waves ----
  __syncthreads();
  if (w == 0) { tl[lane] = t0; tl[64 + lane] = t1; }
  __syncthreads();
  if (w == 1) {
    tot[(size_t)blk * H_ + lane]      = lae_(tl[lane], t0);
    tot[(size_t)blk * H_ + 64 + lane] = lae_(tl[64 + lane], t1);
  }
}

// ---------------- layer 2 final scan -> hbf (bf16) ----------------
__global__ __launch_bounds__(128) void scan3v2_kernel(
    const float* __restrict__ u, const float* __restrict__ A,
    const float* __restrict__ carry, unsigned short* __restrict__ hbf)
{
  int blk = blockIdx.x, ch = threadIdx.x;
  size_t base = (size_t)blk * (CH_ * H_);
  float r = carry[(size_t)blk * H_ + ch];
  const float* up = u + base + ch;
  const float* Ap = A + base + ch;
  unsigned short* hp = hbf + base + ch;
  for (int i0 = 0; i0 < CH_; i0 += 16) {
    float uv[16], av[16];
    #pragma unroll
    for (int i = 0; i < 16; ++i) { uv[i] = up[(i0 + i) * H_]; av[i] = Ap[(i0 + i) * H_]; }
    #pragma unroll
    for (int i = 0; i < 16; ++i) {
      r = lae_(r, uv[i]);
      float e = __expf(av[i] + r);
      float hv = 1.f / (1.f + __expf(-e));
      hp[(size_t)(i0 + i) * H_] = f2bf_(hv);
    }
  }
}

// ---------------- final matmul: out[32,128] = h2flat @ Wout^T + bout --------
__global__ __launch_bounds__(256) void outmm_kernel(
    const unsigned short* __restrict__ hbf,  // 32 x 524288 bf16
    const float* __restrict__ Wout,          // 128 x 524288 fp32
    float* __restrict__ part)
{
  const int KSL = KTOT_ / NKS_;  // 1024
  int tid = threadIdx.x, w = tid >> 6, lane = tid & 63;
  int l15 = lane & 15, quad = lane >> 4;
  int k0base = blockIdx.x * KSL;
  f32x4 acc[2][2] = {{{0,0,0,0},{0,0,0,0}},{{0,0,0,0},{0,0,0,0}}};
  for (int ks = 0; ks < KSL; ks += 32) {
    int k0 = k0base + ks;
    bf16x8 a0 = *reinterpret_cast<const bf16x8*>(
        hbf + (size_t)l15 * KTOT_ + k0 + quad * 8);
    bf16x8 a1 = *reinterpret_cast<const bf16x8*>(
        hbf + (size_t)(16 + l15) * KTOT_ + k0 + quad * 8);
    #pragma unroll
    for (int nt = 0; nt < 2; ++nt) {
      int n = w * 32 + nt * 16 + l15;
      const float* wp = Wout + (size_t)n * KTOT_ + k0 + quad * 8;
      float4 wa = *reinterpret_cast<const float4*>(wp);
      float4 wb = *reinterpret_cast<const float4*>(wp + 4);
      ushort8_t tt;
      tt[0] = f2bf_(wa.x); tt[1] = f2bf_(wa.y); tt[2] = f2bf_(wa.z); tt[3] = f2bf_(wa.w);
      tt[4] = f2bf_(wb.x); tt[5] = f2bf_(wb.y); tt[6] = f2bf_(wb.z); tt[7] = f2bf_(wb.w);
      bf16x8 bf = __builtin_bit_cast(bf16x8, tt);
      acc[0][nt] = __builtin_amdgcn_mfma_f32_16x16x32_bf16(a0, bf, acc[0][nt], 0, 0, 0);
      acc[1][nt] = __builtin_amdgcn_mfma_f32_16x16x32_bf16(a1, bf, acc[1][nt], 0, 0, 0);
    }
  }
  float* pp = part + (size_t)blockIdx.x * (B_ * OUT_);
  #pragma unroll
  for (int mt = 0; mt < 2; ++mt)
    #pragma unroll
    for (int nt = 0; nt < 2; ++nt)
      #pragma unroll
      for (int r = 0; r < 4; ++r) {
        int b = mt * 16 + quad * 4 + r;
        int o = w * 32 + nt * 16 + l15;
        pp[b * OUT_ + o] = acc[mt][nt][r];
      }
}

__global__ __launch_bounds__(256) void outred_kernel(
    const float* __restrict__ part, const float* __restrict__ bout,
    float* __restrict__ out)
{
  int idx = blockIdx.x * 256 + threadIdx.x;  // < 4096
  float s = bout[idx & (OUT_ - 1)];
  for (int wg = 0; wg < NKS_; ++wg) s += part[(size_t)wg * (B_ * OUT_) + idx];
  out[idx] = s;
}

// ---------------- host launcher ----------------
extern "C" void kernel_launch(void* const* d_in, const int* in_sizes, int n_in,
                              void* d_out, int out_size, void* d_ws, size_t ws_size,
                              hipStream_t stream)
{
  const float* x    = (const float*)d_in[0];
  const float* Wz[3] = {(const float*)d_in[1], (const float*)d_in[5], (const float*)d_in[9]};
  const float* bz[3] = {(const float*)d_in[2], (const float*)d_in[6], (const float*)d_in[10]};
  const float* Wh[3] = {(const float*)d_in[3], (const float*)d_in[7], (const float*)d_in[11]};
  const float* bh[3] = {(const float*)d_in[4], (const float*)d_in[8], (const float*)d_in[12]};
  const float* Wout = (const float*)d_in[13];
  const float* bout = (const float*)d_in[14];
  float* out = (float*)d_out;

  char* ws = (char*)d_ws;
  float*          u     = (float*)(ws + 0);                  // 64 MiB
  float*          A     = (float*)(ws + 67108864);           // 64 MiB
  unsigned short* hbf   = (unsigned short*)(ws + 134217728); // 32 MiB
  unsigned short* Wc1   = (unsigned short*)(ws + 167772160); // 64 KiB
  unsigned short* Wc2   = (unsigned short*)(ws + 167837696); // 64 KiB
  float*          tot   = (float*)(ws + 167903232);          // 1 MiB
  float*          carry = (float*)(ws + 168951808);          // 1 MiB
  float*          part  = (float*)(ws + 170000384);          // 8 MiB

  convw2_kernel<<<128, 256, 0, stream>>>(Wz[1], Wh[1], Wz[2], Wh[2], Wc1, Wc2);

  // layer 0 prep + totals
  prep0t_kernel<<<B_ * NC_, 128, 0, stream>>>(x, Wz[0], bz[0], Wh[0], bh[0], u, A, tot);
  scan2_kernel<<<B_, 128, 0, stream>>>(tot, carry);

  // layer 0 -> 1 fused, layer 1 -> 2 fused
  kb_kernel<<<B_ * NC_, 128, 0, stream>>>(carry, Wc1, bz[1], bh[1], u, A, tot);
  scan2_kernel<<<B_, 128, 0, stream>>>(tot, carry);
  kb_kernel<<<B_ * NC_, 128, 0, stream>>>(carry, Wc2, bz[2], bh[2], u, A, tot);
  scan2_kernel<<<B_, 128, 0, stream>>>(tot, carry);

  // layer 2 final scan -> hbf
  scan3v2_kernel<<<B_ * NC_, 128, 0, stream>>>(u, A, carry, hbf);

  // output head
  outmm_kernel<<<NKS_, 256, 0, stream>>>(hbf, Wout, part);
  outred_kernel<<<(B_ * OUT_) / 256, 256, 0, stream>>>(part, bout, out);
}

// Round 3
// 743.747 us; speedup vs baseline: 1.7190x; 1.7190x over previous
//
#include <hip/hip_runtime.h>
#include <hip/hip_bf16.h>
#include <math.h>

// MultiLayerGRUParallel: B=32, S=4096, H=128, OUT=128, L=3
// Fused pipeline: convw2 -> prep0t -> scan2 -> KB(l0->l1) -> scan2 -> KB(l1->l2)
//                 -> scan2 -> scan3v2 -> outmm -> outred
#define B_   32
#define S_   4096
#define H_   128
#define OUT_ 128
#define P_   (B_*S_)       // 131072 positions
#define NC_  64            // time chunks per chain
#define CH_  (S_/NC_)      // 64 steps per chunk
#define NKS_ 512           // split-K workgroups for final matmul
#define KTOT_ (H_*S_)      // 524288
#define NEGINF_ (-__builtin_inff())
#define HTP_ 136           // hT row pitch (ushorts): 272B -> row bank rotates by 4

typedef __bf16 bf16x8 __attribute__((ext_vector_type(8)));
typedef float  f32x4  __attribute__((ext_vector_type(4)));
typedef unsigned short ushort8_t __attribute__((ext_vector_type(8)));

// log1p(x) via hw v_log_f32 — x >= 0 in all our uses; abs err < 1e-7, fine for
// the 5.2e-2 output tolerance. OCML log1pf was ~50 instrs and dominated VALU.
__device__ __forceinline__ float l1p_(float x) { return __logf(1.f + x); }

__device__ __forceinline__ float sp_(float x) {           // softplus, stable
  return fmaxf(x, 0.f) + l1p_(__expf(-fabsf(x)));
}
__device__ __forceinline__ float logg_(float x) {          // _log_g
  return (x >= 0.f) ? __logf(x + 0.5f) : -sp_(-x);
}
__device__ __forceinline__ float lae_(float a, float b) {  // logaddexp
  float m = fmaxf(a, b);
  float d = fminf(a, b) - m;           // lae(-inf, x) = x; never both -inf here
  return m + l1p_(__expf(d));
}
__device__ __forceinline__ float sigm_(float e) {          // sigmoid
  return __builtin_amdgcn_rcpf(1.f + __expf(-e));
}
__device__ __forceinline__ unsigned short f2bf_(float f) { // fp32->bf16 RNE
  unsigned int u = __float_as_uint(f);
  u += 0x7fffu + ((u >> 16) & 1u);
  return (unsigned short)(u >> 16);
}
__device__ __forceinline__ float wscan_(float v) {         // wave64 inclusive +scan
  int lane = threadIdx.x & 63;
  #pragma unroll
  for (int d = 1; d < 64; d <<= 1) {
    float t = __shfl_up(v, (unsigned)d, 64);
    if (lane >= d) v += t;
  }
  return v;
}

// ---------------- weight convert: [Wz;Wh] -> bf16 256x128 for layers 1,2 ----
__global__ __launch_bounds__(256) void convw2_kernel(
    const float* __restrict__ Wz1, const float* __restrict__ Wh1,
    const float* __restrict__ Wz2, const float* __restrict__ Wh2,
    unsigned short* __restrict__ Wc1, unsigned short* __restrict__ Wc2)
{
  int idx = blockIdx.x * 256 + threadIdx.x;  // < 32768
  Wc1[idx] = f2bf_(idx < 16384 ? Wz1[idx] : Wh1[idx - 16384]);
  Wc2[idx] = f2bf_(idx < 16384 ? Wz2[idx] : Wh2[idx - 16384]);
}

// ---------------- layer 0 prep + chunk totals ----------------
// block = one chunk (b,c); 128 thr = 2 waves; wave handles one position/iter.
__global__ __launch_bounds__(128) void prep0t_kernel(
    const float* __restrict__ x,
    const float* __restrict__ Wz, const float* __restrict__ bz,
    const float* __restrict__ Wh, const float* __restrict__ bh,
    float* __restrict__ u, float* __restrict__ A, float* __restrict__ tot)
{
  __shared__ float tl[128];
  int lane = threadIdx.x & 63, wid = threadIdx.x >> 6;
  float wz0 = Wz[lane], wz1 = Wz[lane + 64];
  float bz0 = bz[lane], bz1 = bz[lane + 64];
  float wh0 = Wh[lane], wh1 = Wh[lane + 64];
  float bh0 = bh[lane], bh1 = bh[lane + 64];
  int blk = blockIdx.x;                       // b*NC + c
  size_t base = (size_t)blk * (CH_ * H_);
  int pos0 = blk * CH_;
  float t0 = NEGINF_, t1 = NEGINF_;
  for (int j = 0; j < 32; ++j) {
    int i = j * 2 + wid;
    float xv = x[pos0 + i];
    float k0 = fmaf(xv, wz0, bz0), k1 = fmaf(xv, wz1, bz1);
    float g0 = fmaf(xv, wh0, bh0), g1 = fmaf(xv, wh1, bh1);
    float lc0 = -sp_(k0), lc1 = -sp_(k1);
    float lv0 = k0 + lc0 + logg_(g0);   // -sp(-k) == k - sp(k)
    float lv1 = k1 + lc1 + logg_(g1);
    float s0 = wscan_(lc0);
    float c0 = __shfl(s0, 63, 64);
    float s1 = wscan_(lc1) + c0;
    float u0 = lv0 - s0, u1 = lv1 - s1;
    size_t o = base + (size_t)i * H_;
    u[o + lane]      = u0;  u[o + 64 + lane] = u1;
    A[o + lane]      = s0;  A[o + 64 + lane] = s1;
    t0 = lae_(t0, u0); t1 = lae_(t1, u1);
  }
  if (wid == 0) { tl[lane] = t0; tl[64 + lane] = t1; }
  __syncthreads();
  if (wid == 1) {
    tot[(size_t)blk * H_ + lane]      = lae_(tl[lane], t0);
    tot[(size_t)blk * H_ + 64 + lane] = lae_(tl[64 + lane], t1);
  }
}

// ---------------- inter-chunk carry (tiny) ----------------
__global__ __launch_bounds__(128) void scan2_kernel(
    const float* __restrict__ tot, float* __restrict__ carry)
{
  int b = blockIdx.x, ch = threadIdx.x;
  float r = -0.6931471805599453f;  // log(0.5): the t=0 init value
  for (int c = 0; c < NC_; ++c) {
    size_t idx = (size_t)(b * NC_ + c) * H_ + ch;
    carry[idx] = r;
    r = lae_(r, tot[idx]);
  }
}

// ---------------- fused: scan3(layer l) + matmul xW(l+1) + epilogue + tot ----
// block = one chunk; 128 thr = 2 waves. h stays in LDS (bf16). u/A in-place.
__global__ __launch_bounds__(128) void kb_kernel(
    const float* __restrict__ carry,          // layer l carries
    const unsigned short* __restrict__ Wc,    // layer l+1 [256][128] bf16
    const float* __restrict__ bz, const float* __restrict__ bh,
    float* __restrict__ u, float* __restrict__ A,  // in: layer l, out: layer l+1
    float* __restrict__ tot)                  // out: layer l+1 chunk totals
{
  __shared__ unsigned short hT[64][HTP_]; // 17 KB, h of layer l (bf16), padded
  __shared__ float kg[16][260];           // one 16-row m-tile of [k|g]
  __shared__ float tl[128];
  int tid = threadIdx.x;
  int lane = tid & 63, w = tid >> 6;
  int l15 = lane & 15, quad = lane >> 4;
  int blk = blockIdx.x;
  size_t base = (size_t)blk * (CH_ * H_);

  // ---- phase 1: time-scan of layer l, h -> LDS ----
  {
    int ch = tid;
    float r = carry[(size_t)blk * H_ + ch];
    const float* up = u + base + ch;
    const float* Ap = A + base + ch;
    for (int i0 = 0; i0 < CH_; i0 += 16) {
      float uv[16], av[16];
      #pragma unroll
      for (int i = 0; i < 16; ++i) { uv[i] = up[(i0 + i) * H_]; av[i] = Ap[(i0 + i) * H_]; }
      #pragma unroll
      for (int i = 0; i < 16; ++i) {
        r = lae_(r, uv[i]);
        float hv = sigm_(__expf(av[i] + r));   // sigmoid(exp(log_h))
        hT[i0 + i][ch] = f2bf_(hv);
      }
    }
  }
  __syncthreads();

  float bz0v = bz[lane], bz1v = bz[lane + 64];
  float bh0v = bh[lane], bh1v = bh[lane + 64];
  float t0 = NEGINF_, t1 = NEGINF_;

  // ---- phase 2/3 per 16-row m-tile: MFMA then epilogue ----
  for (int t = 0; t < 4; ++t) {
    f32x4 z = {0.f, 0.f, 0.f, 0.f};
    f32x4 acc[8] = {z, z, z, z, z, z, z, z};
    #pragma unroll
    for (int kk = 0; kk < 4; ++kk) {
      bf16x8 a = *reinterpret_cast<const bf16x8*>(&hT[t * 16 + l15][kk * 32 + quad * 8]);
      #pragma unroll
      for (int nt = 0; nt < 8; ++nt) {
        int n = w * 128 + nt * 16 + l15;   // output col in [k|g] 256
        bf16x8 bf = *reinterpret_cast<const bf16x8*>(Wc + n * 128 + kk * 32 + quad * 8);
        acc[nt] = __builtin_amdgcn_mfma_f32_16x16x32_bf16(a, bf, acc[nt], 0, 0, 0);
      }
    }
    __syncthreads();  // previous epilogue done reading kg
    #pragma unroll
    for (int nt = 0; nt < 8; ++nt) {
      int col = w * 128 + nt * 16 + l15;
      #pragma unroll
      for (int r2 = 0; r2 < 4; ++r2)
        kg[quad * 4 + r2][col] = acc[nt][r2];   // D: row=quad*4+r2, col=l15
    }
    __syncthreads();
    #pragma unroll
    for (int i = 0; i < 8; ++i) {
      int row = w + i * 2;            // wave-interleaved rows of the m-tile
      int sIdx = t * 16 + row;
      float k0 = kg[row][lane]        + bz0v;
      float k1 = kg[row][64 + lane]   + bz1v;
      float g0 = kg[row][128 + lane]  + bh0v;
      float g1 = kg[row][192 + lane]  + bh1v;
      float lc0 = -sp_(k0), lc1 = -sp_(k1);
      float lv0 = k0 + lc0 + logg_(g0);
      float lv1 = k1 + lc1 + logg_(g1);
      float s0 = wscan_(lc0);
      float c0 = __shfl(s0, 63, 64);
      float s1 = wscan_(lc1) + c0;
      float u0 = lv0 - s0, u1 = lv1 - s1;
      size_t o = base + (size_t)sIdx * H_;
      u[o + lane]      = u0;  u[o + 64 + lane] = u1;
      A[o + lane]      = s0;  A[o + 64 + lane] = s1;
      t0 = lae_(t0, u0); t1 = lae_(t1, u1);
    }
  }

  // ---- combine chunk totals across the 2 waves ----
  __syncthreads();
  if (w == 0) { tl[lane] = t0; tl[64 + lane] = t1; }
  __syncthreads();
  if (w == 1) {
    tot[(size_t)blk * H_ + lane]      = lae_(tl[lane], t0);
    tot[(size_t)blk * H_ + 64 + lane] = lae_(tl[64 + lane], t1);
  }
}

// ---------------- layer 2 final scan -> hbf (bf16) ----------------
__global__ __launch_bounds__(128) void scan3v2_kernel(
    const float* __restrict__ u, const float* __restrict__ A,
    const float* __restrict__ carry, unsigned short* __restrict__ hbf)
{
  int blk = blockIdx.x, ch = threadIdx.x;
  size_t base = (size_t)blk * (CH_ * H_);
  float r = carry[(size_t)blk * H_ + ch];
  const float* up = u + base + ch;
  const float* Ap = A + base + ch;
  unsigned short* hp = hbf + base + ch;
  for (int i0 = 0; i0 < CH_; i0 += 16) {
    float uv[16], av[16];
    #pragma unroll
    for (int i = 0; i < 16; ++i) { uv[i] = up[(i0 + i) * H_]; av[i] = Ap[(i0 + i) * H_]; }
    #pragma unroll
    for (int i = 0; i < 16; ++i) {
      r = lae_(r, uv[i]);
      float hv = sigm_(__expf(av[i] + r));
      hp[(size_t)(i0 + i) * H_] = f2bf_(hv);
    }
  }
}

// ---------------- final matmul: out[32,128] = h2flat @ Wout^T + bout --------
__global__ __launch_bounds__(256) void outmm_kernel(
    const unsigned short* __restrict__ hbf,  // 32 x 524288 bf16
    const float* __restrict__ Wout,          // 128 x 524288 fp32
    float* __restrict__ part)
{
  const int KSL = KTOT_ / NKS_;  // 1024
  int tid = threadIdx.x, w = tid >> 6, lane = tid & 63;
  int l15 = lane & 15, quad = lane >> 4;
  int k0base = blockIdx.x * KSL;
  f32x4 acc[2][2] = {{{0,0,0,0},{0,0,0,0}},{{0,0,0,0},{0,0,0,0}}};
  for (int ks = 0; ks < KSL; ks += 32) {
    int k0 = k0base + ks;
    bf16x8 a0 = *reinterpret_cast<const bf16x8*>(
        hbf + (size_t)l15 * KTOT_ + k0 + quad * 8);
    bf16x8 a1 = *reinterpret_cast<const bf16x8*>(
        hbf + (size_t)(16 + l15) * KTOT_ + k0 + quad * 8);
    #pragma unroll
    for (int nt = 0; nt < 2; ++nt) {
      int n = w * 32 + nt * 16 + l15;
      const float* wp = Wout + (size_t)n * KTOT_ + k0 + quad * 8;
      float4 wa = *reinterpret_cast<const float4*>(wp);
      float4 wb = *reinterpret_cast<const float4*>(wp + 4);
      ushort8_t tt;
      tt[0] = f2bf_(wa.x); tt[1] = f2bf_(wa.y); tt[2] = f2bf_(wa.z); tt[3] = f2bf_(wa.w);
      tt[4] = f2bf_(wb.x); tt[5] = f2bf_(wb.y); tt[6] = f2bf_(wb.z); tt[7] = f2bf_(wb.w);
      bf16x8 bf = __builtin_bit_cast(bf16x8, tt);
      acc[0][nt] = __builtin_amdgcn_mfma_f32_16x16x32_bf16(a0, bf, acc[0][nt], 0, 0, 0);
      acc[1][nt] = __builtin_amdgcn_mfma_f32_16x16x32_bf16(a1, bf, acc[1][nt], 0, 0, 0);
    }
  }
  float* pp = part + (size_t)blockIdx.x * (B_ * OUT_);
  #pragma unroll
  for (int mt = 0; mt < 2; ++mt)
    #pragma unroll
    for (int nt = 0; nt < 2; ++nt)
      #pragma unroll
      for (int r = 0; r < 4; ++r) {
        int b = mt * 16 + quad * 4 + r;
        int o = w * 32 + nt * 16 + l15;
        pp[b * OUT_ + o] = acc[mt][nt][r];
      }
}

// 4 outputs per block (one per wave); lanes stride the 512 partials.
__global__ __launch_bounds__(256) void outred_kernel(
    const float* __restrict__ part, const float* __restrict__ bout,
    float* __restrict__ out)
{
  int w = threadIdx.x >> 6, lane = threadIdx.x & 63;
  int idx = blockIdx.x * 4 + w;  // < 4096
  float s = 0.f;
  for (int wg = lane; wg < NKS_; wg += 64) s += part[(size_t)wg * (B_ * OUT_) + idx];
  #pragma unroll
  for (int d = 32; d; d >>= 1) s += __shfl_down(s, (unsigned)d, 64);
  if (lane == 0) out[idx] = s + bout[idx & (OUT_ - 1)];
}

// ---------------- host launcher ----------------
extern "C" void kernel_launch(void* const* d_in, const int* in_sizes, int n_in,
                              void* d_out, int out_size, void* d_ws, size_t ws_size,
                              hipStream_t stream)
{
  const float* x    = (const float*)d_in[0];
  const float* Wz[3] = {(const float*)d_in[1], (const float*)d_in[5], (const float*)d_in[9]};
  const float* bz[3] = {(const float*)d_in[2], (const float*)d_in[6], (const float*)d_in[10]};
  const float* Wh[3] = {(const float*)d_in[3], (const float*)d_in[7], (const float*)d_in[11]};
  const float* bh[3] = {(const float*)d_in[4], (const float*)d_in[8], (const float*)d_in[12]};
  const float* Wout = (const float*)d_in[13];
  const float* bout = (const float*)d_in[14];
  float* out = (float*)d_out;

  char* ws = (char*)d_ws;
  float*          u     = (float*)(ws + 0);                  // 64 MiB
  float*          A     = (float*)(ws + 67108864);           // 64 MiB
  unsigned short* hbf   = (unsigned short*)(ws + 134217728); // 32 MiB
  unsigned short* Wc1   = (unsigned short*)(ws + 167772160); // 64 KiB
  unsigned short* Wc2   = (unsigned short*)(ws + 167837696); // 64 KiB
  float*          tot   = (float*)(ws + 167903232);          // 1 MiB
  float*          carry = (float*)(ws + 168951808);          // 1 MiB
  float*          part  = (float*)(ws + 170000384);          // 8 MiB

  convw2_kernel<<<128, 256, 0, stream>>>(Wz[1], Wh[1], Wz[2], Wh[2], Wc1, Wc2);

  // layer 0 prep + totals
  prep0t_kernel<<<B_ * NC_, 128, 0, stream>>>(x, Wz[0], bz[0], Wh[0], bh[0], u, A, tot);
  scan2_kernel<<<B_, 128, 0, stream>>>(tot, carry);

  // layer 0 -> 1 fused, layer 1 -> 2 fused
  kb_kernel<<<B_ * NC_, 128, 0, stream>>>(carry, Wc1, bz[1], bh[1], u, A, tot);
  scan2_kernel<<<B_, 128, 0, stream>>>(tot, carry);
  kb_kernel<<<B_ * NC_, 128, 0, stream>>>(carry, Wc2, bz[2], bh[2], u, A, tot);
  scan2_kernel<<<B_, 128, 0, stream>>>(tot, carry);

  // layer 2 final scan -> hbf
  scan3v2_kernel<<<B_ * NC_, 128, 0, stream>>>(u, A, carry, hbf);

  // output head
  outmm_kernel<<<NKS_, 256, 0, stream>>>(hbf, Wout, part);
  outred_kernel<<<(B_ * OUT_) / 4, 256, 0, stream>>>(part, bout, out);
}

// Round 4
// 666.968 us; speedup vs baseline: 1.9169x; 1.1151x over previous
//
#include <hip/hip_runtime.h>
#include <hip/hip_bf16.h>
#include <math.h>

// MultiLayerGRUParallel: B=32, S=4096, H=128, OUT=128, L=3
// Fused pipeline: convw2 -> prep0t -> scan2 -> KB(l0->l1) -> scan2 -> KB(l1->l2)
//                 -> scan2 -> scan3v2 -> outmm -> outred
#define B_   32
#define S_   4096
#define H_   128
#define OUT_ 128
#define P_   (B_*S_)       // 131072 positions
#define NC_  64            // time chunks per chain
#define CH_  (S_/NC_)      // 64 steps per chunk
#define NKS_ 512           // split-K workgroups for final matmul
#define KTOT_ (H_*S_)      // 524288
#define NEGINF_ (-__builtin_inff())
#define HTP_ 136           // hT row pitch (ushorts): 272B -> row bank rotates by 4

typedef __bf16 bf16x8 __attribute__((ext_vector_type(8)));
typedef float  f32x4  __attribute__((ext_vector_type(4)));
typedef unsigned short ushort8_t __attribute__((ext_vector_type(8)));

// ---- fast math (|args| bounded <~10 in this net; tolerance 5.2e-2) ----
__device__ __forceinline__ float sp_(float x) {            // softplus
  return __logf(1.f + __expf(x));
}
__device__ __forceinline__ float logg_(float x) {          // _log_g
  // x>=0: log(x+0.5); x<0: -sp(-x) = log(sigmoid(x))
  float t = (x >= 0.f) ? (x + 0.5f) : __builtin_amdgcn_rcpf(1.f + __expf(-x));
  return __logf(t);
}
__device__ __forceinline__ float lae_(float a, float b) {  // logaddexp
  float m = fmaxf(a, b);
  float d = -fabsf(a - b);                 // lae(-inf,x)=x fine
  return m + __logf(1.f + __expf(d));
}
__device__ __forceinline__ float sigm_(float e) {          // sigmoid
  return __builtin_amdgcn_rcpf(1.f + __expf(-e));
}
__device__ __forceinline__ unsigned short f2bf_(float f) { // fp32->bf16 RNE
  unsigned int u = __float_as_uint(f);
  u += 0x7fffu + ((u >> 16) & 1u);
  return (unsigned short)(u >> 16);
}

// DPP inclusive add-scan over 64 lanes: 6 VALU ops, no LDS pipe.
#define DPPADD_(v, ctrl, rmask) \
  ((v) + __int_as_float(__builtin_amdgcn_update_dpp( \
      0, __float_as_int(v), (ctrl), (rmask), 0xf, true)))
__device__ __forceinline__ float wscan_(float v) {
  v = DPPADD_(v, 0x111, 0xf);  // row_shr:1
  v = DPPADD_(v, 0x112, 0xf);  // row_shr:2
  v = DPPADD_(v, 0x114, 0xf);  // row_shr:4
  v = DPPADD_(v, 0x118, 0xf);  // row_shr:8
  v = DPPADD_(v, 0x142, 0xa);  // row_bcast:15 -> rows 1,3
  v = DPPADD_(v, 0x143, 0xc);  // row_bcast:31 -> rows 2,3
  return v;
}

// ---------------- weight convert: [Wz;Wh] -> bf16 256x128 for layers 1,2 ----
__global__ __launch_bounds__(256) void convw2_kernel(
    const float* __restrict__ Wz1, const float* __restrict__ Wh1,
    const float* __restrict__ Wz2, const float* __restrict__ Wh2,
    unsigned short* __restrict__ Wc1, unsigned short* __restrict__ Wc2)
{
  int idx = blockIdx.x * 256 + threadIdx.x;  // < 32768
  Wc1[idx] = f2bf_(idx < 16384 ? Wz1[idx] : Wh1[idx - 16384]);
  Wc2[idx] = f2bf_(idx < 16384 ? Wz2[idx] : Wh2[idx - 16384]);
}

// ---------------- layer 0 prep + chunk totals ----------------
// block = one chunk; 256 thr = 4 waves; wave handles one position per iter.
__global__ __launch_bounds__(256) void prep0t_kernel(
    const float* __restrict__ x,
    const float* __restrict__ Wz, const float* __restrict__ bz,
    const float* __restrict__ Wh, const float* __restrict__ bh,
    float* __restrict__ u, float* __restrict__ A, float* __restrict__ tot)
{
  __shared__ float tpart[4][128];
  int lane = threadIdx.x & 63, w = threadIdx.x >> 6;
  float wz0 = Wz[lane], wz1 = Wz[lane + 64];
  float bz0 = bz[lane], bz1 = bz[lane + 64];
  float wh0 = Wh[lane], wh1 = Wh[lane + 64];
  float bh0 = bh[lane], bh1 = bh[lane + 64];
  int blk = blockIdx.x;                       // b*NC + c
  size_t base = (size_t)blk * (CH_ * H_);
  int pos0 = blk * CH_;
  float t0 = NEGINF_, t1 = NEGINF_;
  for (int j = 0; j < 16; ++j) {
    int i = j * 4 + w;
    float xv = x[pos0 + i];
    float k0 = fmaf(xv, wz0, bz0), k1 = fmaf(xv, wz1, bz1);
    float g0 = fmaf(xv, wh0, bh0), g1 = fmaf(xv, wh1, bh1);
    float lc0 = -sp_(k0), lc1 = -sp_(k1);
    float lv0 = k0 + lc0 + logg_(g0);   // -sp(-k) == k - sp(k)
    float lv1 = k1 + lc1 + logg_(g1);
    float s0 = wscan_(lc0);
    float c0 = __shfl(s0, 63, 64);
    float s1 = wscan_(lc1) + c0;
    float u0 = lv0 - s0, u1 = lv1 - s1;
    size_t o = base + (size_t)i * H_;
    u[o + lane]      = u0;  u[o + 64 + lane] = u1;
    A[o + lane]      = s0;  A[o + 64 + lane] = s1;
    t0 = lae_(t0, u0); t1 = lae_(t1, u1);
  }
  tpart[w][lane] = t0; tpart[w][64 + lane] = t1;
  __syncthreads();
  if (w == 0) {
    int ch = lane;
    tot[(size_t)blk * H_ + ch] =
        lae_(lae_(tpart[0][ch], tpart[1][ch]), lae_(tpart[2][ch], tpart[3][ch]));
    ch = lane + 64;
    tot[(size_t)blk * H_ + ch] =
        lae_(lae_(tpart[0][ch], tpart[1][ch]), lae_(tpart[2][ch], tpart[3][ch]));
  }
}

// ---------------- inter-chunk carry (tiny) ----------------
__global__ __launch_bounds__(128) void scan2_kernel(
    const float* __restrict__ tot, float* __restrict__ carry)
{
  int b = blockIdx.x, ch = threadIdx.x;
  float r = -0.6931471805599453f;  // log(0.5): the t=0 init value
  for (int c = 0; c < NC_; ++c) {
    size_t idx = (size_t)(b * NC_ + c) * H_ + ch;
    carry[idx] = r;
    r = lae_(r, tot[idx]);
  }
}

// ---------------- fused: scan3(layer l) + matmul xW(l+1) + epilogue + tot ----
// block = one chunk; 256 thr = 4 waves. h stays in LDS (bf16). u/A in-place.
// Phase 1 split-chain: half0 = positions 0..31 (true carry), half1 = 32..63
// (local scan -> LDS, fixup after sync). Halves the serial lae latency.
__global__ __launch_bounds__(256) void kb_kernel(
    const float* __restrict__ carry,          // layer l carries
    const unsigned short* __restrict__ Wc,    // layer l+1 [256][128] bf16
    const float* __restrict__ bz, const float* __restrict__ bh,
    float* __restrict__ u, float* __restrict__ A,  // in: layer l, out: layer l+1
    float* __restrict__ tot)                  // out: layer l+1 chunk totals
{
  __shared__ unsigned short hT[64][HTP_]; // 17.0 KB h of layer l (bf16), padded
  __shared__ float kg[16][260];           // 16.6 KB one 16-row m-tile of [k|g]
  __shared__ float scr[32][128];          // 16 KB half1 local scans
  __shared__ float thand[128];            // half0 -> half1 carry handoff
  __shared__ float tpart[4][128];         // per-wave tot partials
  int tid = threadIdx.x;
  int lane = tid & 63, w = tid >> 6;
  int l15 = lane & 15, quad = lane >> 4;
  int half = tid >> 7, ch = tid & 127;
  int blk = blockIdx.x;
  size_t base = (size_t)blk * (CH_ * H_);

  // ---- phase 1a ----
  if (half == 0) {
    float r = carry[(size_t)blk * H_ + ch];
    const float* up = u + base + ch;
    const float* Ap = A + base + ch;
    for (int i0 = 0; i0 < 32; i0 += 16) {
      float uv[16], av[16];
      #pragma unroll
      for (int i = 0; i < 16; ++i) { uv[i] = up[(i0 + i) * H_]; av[i] = Ap[(i0 + i) * H_]; }
      #pragma unroll
      for (int i = 0; i < 16; ++i) {
        r = lae_(r, uv[i]);
        hT[i0 + i][ch] = f2bf_(sigm_(__expf(av[i] + r)));
      }
    }
    thand[ch] = r;   // carry into position 32
  } else {
    float r = NEGINF_;
    const float* up = u + base + ch;
    for (int i0 = 0; i0 < 32; i0 += 16) {
      float uv[16];
      #pragma unroll
      for (int i = 0; i < 16; ++i) uv[i] = up[(32 + i0 + i) * H_];
      #pragma unroll
      for (int i = 0; i < 16; ++i) { r = lae_(r, uv[i]); scr[i0 + i][ch] = r; }
    }
  }
  __syncthreads();
  // ---- phase 1b: half1 fixup with half0's carry ----
  if (half == 1) {
    float r31 = thand[ch];
    const float* Ap = A + base + ch;
    for (int i0 = 0; i0 < 32; i0 += 16) {
      float av[16];
      #pragma unroll
      for (int i = 0; i < 16; ++i) av[i] = Ap[(32 + i0 + i) * H_];
      #pragma unroll
      for (int i = 0; i < 16; ++i) {
        float ri = lae_(r31, scr[i0 + i][ch]);
        hT[32 + i0 + i][ch] = f2bf_(sigm_(__expf(av[i] + ri)));
      }
    }
  }
  __syncthreads();

  float bz0v = bz[lane], bz1v = bz[lane + 64];
  float bh0v = bh[lane], bh1v = bh[lane + 64];
  float t0 = NEGINF_, t1 = NEGINF_;

  // ---- phase 2/3 per 16-row m-tile: MFMA then epilogue ----
  // wave w owns output cols [64w, 64w+64) of N=256 ([k|g]).
  for (int t = 0; t < 4; ++t) {
    f32x4 z = {0.f, 0.f, 0.f, 0.f};
    f32x4 acc[4] = {z, z, z, z};
    #pragma unroll
    for (int kk = 0; kk < 4; ++kk) {
      bf16x8 a = *reinterpret_cast<const bf16x8*>(&hT[t * 16 + l15][kk * 32 + quad * 8]);
      #pragma unroll
      for (int nt = 0; nt < 4; ++nt) {
        int n = w * 64 + nt * 16 + l15;
        bf16x8 bf = *reinterpret_cast<const bf16x8*>(Wc + n * 128 + kk * 32 + quad * 8);
        acc[nt] = __builtin_amdgcn_mfma_f32_16x16x32_bf16(a, bf, acc[nt], 0, 0, 0);
      }
    }
    __syncthreads();  // previous epilogue done reading kg
    #pragma unroll
    for (int nt = 0; nt < 4; ++nt) {
      int col = w * 64 + nt * 16 + l15;
      #pragma unroll
      for (int r2 = 0; r2 < 4; ++r2)
        kg[quad * 4 + r2][col] = acc[nt][r2];   // D: row=quad*4+r2, col=l15
    }
    __syncthreads();
    #pragma unroll
    for (int i = 0; i < 4; ++i) {
      int row = w + i * 4;            // wave-interleaved rows of the m-tile
      int sIdx = t * 16 + row;
      float k0 = kg[row][lane]        + bz0v;
      float k1 = kg[row][64 + lane]   + bz1v;
      float g0 = kg[row][128 + lane]  + bh0v;
      float g1 = kg[row][192 + lane]  + bh1v;
      float lc0 = -sp_(k0), lc1 = -sp_(k1);
      float lv0 = k0 + lc0 + logg_(g0);
      float lv1 = k1 + lc1 + logg_(g1);
      float s0 = wscan_(lc0);
      float c0 = __shfl(s0, 63, 64);
      float s1 = wscan_(lc1) + c0;
      float u0 = lv0 - s0, u1 = lv1 - s1;
      size_t o = base + (size_t)sIdx * H_;
      u[o + lane]      = u0;  u[o + 64 + lane] = u1;
      A[o + lane]      = s0;  A[o + 64 + lane] = s1;
      t0 = lae_(t0, u0); t1 = lae_(t1, u1);
    }
  }

  // ---- combine chunk totals across the 4 waves ----
  tpart[w][lane] = t0; tpart[w][64 + lane] = t1;
  __syncthreads();
  if (w == 0) {
    int c = lane;
    tot[(size_t)blk * H_ + c] =
        lae_(lae_(tpart[0][c], tpart[1][c]), lae_(tpart[2][c], tpart[3][c]));
    c = lane + 64;
    tot[(size_t)blk * H_ + c] =
        lae_(lae_(tpart[0][c], tpart[1][c]), lae_(tpart[2][c], tpart[3][c]));
  }
}

// ---------------- layer 2 final scan -> hbf (bf16), split-chain ------------
__global__ __launch_bounds__(256) void scan3v2_kernel(
    const float* __restrict__ u, const float* __restrict__ A,
    const float* __restrict__ carry, unsigned short* __restrict__ hbf)
{
  __shared__ float scr[32][128];
  __shared__ float thand[128];
  int tid = threadIdx.x;
  int half = tid >> 7, ch = tid & 127;
  int blk = blockIdx.x;
  size_t base = (size_t)blk * (CH_ * H_);
  const float* up = u + base + ch;
  const float* Ap = A + base + ch;
  unsigned short* hp = hbf + base + ch;
  if (half == 0) {
    float r = carry[(size_t)blk * H_ + ch];
    for (int i0 = 0; i0 < 32; i0 += 16) {
      float uv[16], av[16];
      #pragma unroll
      for (int i = 0; i < 16; ++i) { uv[i] = up[(i0 + i) * H_]; av[i] = Ap[(i0 + i) * H_]; }
      #pragma unroll
      for (int i = 0; i < 16; ++i) {
        r = lae_(r, uv[i]);
        hp[(size_t)(i0 + i) * H_] = f2bf_(sigm_(__expf(av[i] + r)));
      }
    }
    thand[ch] = r;
  } else {
    float r = NEGINF_;
    for (int i0 = 0; i0 < 32; i0 += 16) {
      float uv[16];
      #pragma unroll
      for (int i = 0; i < 16; ++i) uv[i] = up[(32 + i0 + i) * H_];
      #pragma unroll
      for (int i = 0; i < 16; ++i) { r = lae_(r, uv[i]); scr[i0 + i][ch] = r; }
    }
  }
  __syncthreads();
  if (half == 1) {
    float r31 = thand[ch];
    for (int i0 = 0; i0 < 32; i0 += 16) {
      float av[16];
      #pragma unroll
      for (int i = 0; i < 16; ++i) av[i] = Ap[(32 + i0 + i) * H_];
      #pragma unroll
      for (int i = 0; i < 16; ++i) {
        float ri = lae_(r31, scr[i0 + i][ch]);
        hp[(size_t)(32 + i0 + i) * H_] = f2bf_(sigm_(__expf(av[i] + ri)));
      }
    }
  }
}

// ---------------- final matmul: out[32,128] = h2flat @ Wout^T + bout --------
__global__ __launch_bounds__(256) void outmm_kernel(
    const unsigned short* __restrict__ hbf,  // 32 x 524288 bf16
    const float* __restrict__ Wout,          // 128 x 524288 fp32
    float* __restrict__ part)
{
  const int KSL = KTOT_ / NKS_;  // 1024
  int tid = threadIdx.x, w = tid >> 6, lane = tid & 63;
  int l15 = lane & 15, quad = lane >> 4;
  int k0base = blockIdx.x * KSL;
  f32x4 acc[2][2] = {{{0,0,0,0},{0,0,0,0}},{{0,0,0,0},{0,0,0,0}}};
  for (int ks = 0; ks < KSL; ks += 32) {
    int k0 = k0base + ks;
    bf16x8 a0 = *reinterpret_cast<const bf16x8*>(
        hbf + (size_t)l15 * KTOT_ + k0 + quad * 8);
    bf16x8 a1 = *reinterpret_cast<const bf16x8*>(
        hbf + (size_t)(16 + l15) * KTOT_ + k0 + quad * 8);
    #pragma unroll
    for (int nt = 0; nt < 2; ++nt) {
      int n = w * 32 + nt * 16 + l15;
      const float* wp = Wout + (size_t)n * KTOT_ + k0 + quad * 8;
      float4 wa = *reinterpret_cast<const float4*>(wp);
      float4 wb = *reinterpret_cast<const float4*>(wp + 4);
      ushort8_t tt;
      tt[0] = f2bf_(wa.x); tt[1] = f2bf_(wa.y); tt[2] = f2bf_(wa.z); tt[3] = f2bf_(wa.w);
      tt[4] = f2bf_(wb.x); tt[5] = f2bf_(wb.y); tt[6] = f2bf_(wb.z); tt[7] = f2bf_(wb.w);
      bf16x8 bf = __builtin_bit_cast(bf16x8, tt);
      acc[0][nt] = __builtin_amdgcn_mfma_f32_16x16x32_bf16(a0, bf, acc[0][nt], 0, 0, 0);
      acc[1][nt] = __builtin_amdgcn_mfma_f32_16x16x32_bf16(a1, bf, acc[1][nt], 0, 0, 0);
    }
  }
  float* pp = part + (size_t)blockIdx.x * (B_ * OUT_);
  #pragma unroll
  for (int mt = 0; mt < 2; ++mt)
    #pragma unroll
    for (int nt = 0; nt < 2; ++nt)
      #pragma unroll
      for (int r = 0; r < 4; ++r) {
        int b = mt * 16 + quad * 4 + r;
        int o = w * 32 + nt * 16 + l15;
        pp[b * OUT_ + o] = acc[mt][nt][r];
      }
}

// 4 outputs per block (one per wave); lanes stride the 512 partials.
__global__ __launch_bounds__(256) void outred_kernel(
    const float* __restrict__ part, const float* __restrict__ bout,
    float* __restrict__ out)
{
  int w = threadIdx.x >> 6, lane = threadIdx.x & 63;
  int idx = blockIdx.x * 4 + w;  // < 4096
  float s = 0.f;
  for (int wg = lane; wg < NKS_; wg += 64) s += part[(size_t)wg * (B_ * OUT_) + idx];
  #pragma unroll
  for (int d = 32; d; d >>= 1) s += __shfl_down(s, (unsigned)d, 64);
  if (lane == 0) out[idx] = s + bout[idx & (OUT_ - 1)];
}

// ---------------- host launcher ----------------
extern "C" void kernel_launch(void* const* d_in, const int* in_sizes, int n_in,
                              void* d_out, int out_size, void* d_ws, size_t ws_size,
                              hipStream_t stream)
{
  const float* x    = (const float*)d_in[0];
  const float* Wz[3] = {(const float*)d_in[1], (const float*)d_in[5], (const float*)d_in[9]};
  const float* bz[3] = {(const float*)d_in[2], (const float*)d_in[6], (const float*)d_in[10]};
  const float* Wh[3] = {(const float*)d_in[3], (const float*)d_in[7], (const float*)d_in[11]};
  const float* bh[3] = {(const float*)d_in[4], (const float*)d_in[8], (const float*)d_in[12]};
  const float* Wout = (const float*)d_in[13];
  const float* bout = (const float*)d_in[14];
  float* out = (float*)d_out;

  char* ws = (char*)d_ws;
  float*          u     = (float*)(ws + 0);                  // 64 MiB
  float*          A     = (float*)(ws + 67108864);           // 64 MiB
  unsigned short* hbf   = (unsigned short*)(ws + 134217728); // 32 MiB
  unsigned short* Wc1   = (unsigned short*)(ws + 167772160); // 64 KiB
  unsigned short* Wc2   = (unsigned short*)(ws + 167837696); // 64 KiB
  float*          tot   = (float*)(ws + 167903232);          // 1 MiB
  float*          carry = (float*)(ws + 168951808);          // 1 MiB
  float*          part  = (float*)(ws + 170000384);          // 8 MiB

  convw2_kernel<<<128, 256, 0, stream>>>(Wz[1], Wh[1], Wz[2], Wh[2], Wc1, Wc2);

  // layer 0 prep + totals
  prep0t_kernel<<<B_ * NC_, 256, 0, stream>>>(x, Wz[0], bz[0], Wh[0], bh[0], u, A, tot);
  scan2_kernel<<<B_, 128, 0, stream>>>(tot, carry);

  // layer 0 -> 1 fused, layer 1 -> 2 fused
  kb_kernel<<<B_ * NC_, 256, 0, stream>>>(carry, Wc1, bz[1], bh[1], u, A, tot);
  scan2_kernel<<<B_, 128, 0, stream>>>(tot, carry);
  kb_kernel<<<B_ * NC_, 256, 0, stream>>>(carry, Wc2, bz[2], bh[2], u, A, tot);
  scan2_kernel<<<B_, 128, 0, stream>>>(tot, carry);

  // layer 2 final scan -> hbf
  scan3v2_kernel<<<B_ * NC_, 256, 0, stream>>>(u, A, carry, hbf);

  // output head
  outmm_kernel<<<NKS_, 256, 0, stream>>>(hbf, Wout, part);
  outred_kernel<<<(B_ * OUT_) / 4, 256, 0, stream>>>(part, bout, out);
}